// Round 12
// baseline (253.460 us; speedup 1.0000x reference)
//
#include <hip/hip_runtime.h>
#include <stdint.h>

// No implicit FMA contraction: the JAX eager reference has none across ops;
// where XLA fuses we write fmaf() explicitly.
#pragma clang fp contract(off)

#define PDIM 162
#define NW   (2*PDIM*PDIM*3)   // 157464 words, 1.26 MB per bitboard
#define NWH  (NW/2)            // 78732
#define OD   160

// LDS tile: 32 z-rows x 32 y-rows x 3 words, addr lz*97 + ly*3 + w.
// 97 u64 = 194 dwords == 2 mod 32. Row-triple ge2 lanes (Dly=1 -> 6-dword
// stride) give adjacent non-overlapping footprints: full-BW, conflict-free.
#define PZ 97
#define LADDR(lz,ly) ((lz)*PZ + (ly)*3)

// ---------------- threefry2x32, JAX partitionable scheme --------------------
__device__ __forceinline__ uint32_t rotl32(uint32_t x, uint32_t r) {
  return (x << r) | (x >> (32u - r));
}

__device__ __forceinline__ uint32_t threefry_bits(uint32_t idx) {
  const uint32_t ks0 = 0u, ks1 = 42u, ks2 = 0x1BD11BDAu ^ 0u ^ 42u;
  uint32_t x0 = 0u + ks0;
  uint32_t x1 = idx + ks1;
#define TFR(r) { x0 += x1; x1 = rotl32(x1, (r)); x1 ^= x0; }
  TFR(13u) TFR(15u) TFR(26u) TFR(6u)
  x0 += ks1; x1 += ks2 + 1u;
  TFR(17u) TFR(29u) TFR(16u) TFR(24u)
  x0 += ks2; x1 += ks0 + 2u;
  TFR(13u) TFR(15u) TFR(26u) TFR(6u)
  x0 += ks0; x1 += ks1 + 3u;
  TFR(17u) TFR(29u) TFR(16u) TFR(24u)
  x0 += ks1; x1 += ks2 + 4u;
  TFR(13u) TFR(15u) TFR(26u) TFR(6u)
  x0 += ks2; x1 += ks0 + 5u;
#undef TFR
  return x0 ^ x1;
}

// ------------- XLA-CPU (Cephes) float32 log replication ---------------------
__device__ __forceinline__ float xla_logf(float xin) {
  uint32_t bits = __float_as_uint(xin);
  float e = (float)((int)(bits >> 23) - 126);
  float x = __uint_as_float((bits & 0x007fffffu) | 0x3f000000u);
  const float SQRTHF = 0.707106781186547524f;
  bool lt = (x < SQRTHF);
  float tmp = lt ? x : 0.0f;
  e = e - (lt ? 1.0f : 0.0f);
  x = x - 1.0f;
  x = x + tmp;
  float z = x * x;
  float y = 7.0376836292e-2f;
  y = fmaf(y, x, -1.1514610310e-1f);
  y = fmaf(y, x,  1.1676998740e-1f);
  y = fmaf(y, x, -1.2420140846e-1f);
  y = fmaf(y, x,  1.4249322787e-1f);
  y = fmaf(y, x, -1.6668057665e-1f);
  y = fmaf(y, x,  2.0000714765e-1f);
  y = fmaf(y, x, -2.4999993993e-1f);
  y = fmaf(y, x,  3.3333331174e-1f);
  y = y * x;
  y = y * z;
  y = fmaf(e, -2.12194440e-4f, y);
  y = fmaf(-0.5f, z, y);
  x = x + y;
  x = fmaf(e, 0.693359375f, x);
  return x;
}

__device__ __forceinline__ float xla_log1pf(float x) {
  float for_large = xla_logf(x + 1.0f);
  float for_small = fmaf(-0.5f, x, 1.0f) * x;
  return (fabsf(x) < 1e-4f) ? for_small : for_large;
}

// one voxel's decision (exact JAX/XLA bit replication)
__device__ __forceinline__ bool bin_pred(const float* __restrict__ in, uint32_t w,
                                         uint32_t lane) {
  uint32_t row = w / 3u, wx = w - row * 3u;
  uint32_t n  = row / (uint32_t)(PDIM * PDIM);
  uint32_t rr = row - n * (uint32_t)(PDIM * PDIM);
  uint32_t z  = rr / (uint32_t)PDIM;
  uint32_t y  = rr - z * (uint32_t)PDIM;
  uint32_t x  = wx * 64u + lane;
  // pad voxels are provably 0: |0.33*noise| <= 6.08 < 18.42 = |log alpha(0)|
  if ((z - 1u) >= 160u || (y - 1u) >= 160u || (x - 1u) >= 160u) return false;
  float v = in[((n * 160u + (z - 1u)) * 160u + (y - 1u)) * 160u + (x - 1u)];
  uint32_t i = row * 162u + x;            // flat padded index for RNG
  uint32_t b = threefry_bits(i);
  float f  = __uint_as_float((b >> 9) | 0x3f800000u) - 1.0f;
  float uu = fmaxf(1e-8f, f + 1e-8f);
  float la = xla_logf((v + 1e-8f) / ((1.0f - v) + 1e-8f));
  float noise = xla_logf(uu) - xla_log1pf(-uu);
  float zs = la + noise * 0.33f;
  return (zs > 1.1920928955078125e-7f);   // logistic>0.5 iff z>2^-23
}

// ---------------------------- binarize --------------------------------------
// ILP-2: each wave produces TWO words (w and w+NW/2).
__global__ __launch_bounds__(256) void k_binarize(const float* __restrict__ in,
                                                  uint64_t* __restrict__ bits) {
  uint32_t t = blockIdx.x * 256u + threadIdx.x;
  uint32_t w0 = t >> 6, lane = t & 63u;
  if (w0 >= (uint32_t)NWH) return;        // wave-uniform
  uint32_t w1 = w0 + (uint32_t)NWH;
  bool p0 = bin_pred(in, w0, lane);
  bool p1 = bin_pred(in, w1, lane);
  uint64_t m0 = __ballot(p0);
  uint64_t m1 = __ballot(p1);
  if (lane == 0) { bits[w0] = m0; bits[w1] = m1; }
}

// --------- per-word neighborhood expansion from a register row-tile ---------
#define NB(dz,dy,dx) ((dx)==-1 ? Lb[(dz)+1][(dy)+1] : ((dx)==1 ? Rb[(dz)+1][(dy)+1] : Vv[(dz)+1][(dy)+1]))

#define EXPAND_W(w_) \
  _Pragma("unroll") \
  for (int dz = 0; dz < 3; ++dz) \
    _Pragma("unroll") \
    for (int dy = 0; dy < 3; ++dy) { \
      uint64_t b = R[dz][dy][w_]; \
      uint64_t a = ((w_) > 0) ? R[dz][dy][(w_)-1] : 0ull; \
      uint64_t d = ((w_) < 2) ? R[dz][dy][(w_)+1] : 0ull; \
      Vv[dz][dy] = b; \
      Lb[dz][dy] = (b << 1) | (a >> 63); \
      Rb[dz][dy] = (b >> 1) | (d << 63); \
    }

#define LOAD_R(SRC, lz, ly) \
  _Pragma("unroll") \
  for (int dz = 0; dz < 3; ++dz) \
    _Pragma("unroll") \
    for (int dy = 0; dy < 3; ++dy) { \
      int rb = LADDR((lz) + dz - 1, (ly) + dy - 1); \
      R[dz][dy][0] = SRC[rb]; R[dz][dy][1] = SRC[rb + 1]; R[dz][dy][2] = SRC[rb + 2]; \
    }

// ---------------------------- iteration kernel ------------------------------
// One block: 16x16 (z,y) core x full 192-bit x, halo 8 -> 32x32 LDS tile.
// Thread task = one (z,y) row TRIPLE: one 27-word gather serves 3 word results
// (3x fewer wave-level LDS instructions than word-tasks, addressing amortized).
__global__ __launch_bounds__(1024) void k_iter(const uint64_t* __restrict__ bin,
                                               uint64_t* __restrict__ bout,
                                               float4* __restrict__ outf,
                                               int zero_pads) {
  __shared__ uint64_t Bt[32 * PZ];
  __shared__ uint64_t Ge[32 * PZ];
  const int tid = threadIdx.x;
  const int bid = blockIdx.x;
  const int n  = bid / 100;
  const int rm = bid - n * 100;
  const int tz = rm / 10, ty = rm - tz * 10;
  const int gz0 = 1 + 16 * tz, gy0 = 1 + 16 * ty;   // both odd

  // Zero bout's pad rows (z or y in {0,161}) once per replay (block 0, iter 1).
  if (zero_pads && bid == 0) {
    for (int j = tid; j < 1288; j += 1024) {
      int nn, z, y;
      if (j < 648) { nn = j / 324; int r = j - nn * 324;
                     z = (r >= 162) ? 161 : 0; y = (r >= 162) ? r - 162 : r; }
      else { int j2 = j - 648; nn = j2 / 320; int r = j2 - nn * 320;
             y = (r >= 160) ? 161 : 0; z = 1 + ((r >= 160) ? r - 160 : r); }
      uint64_t* p = bout + (((nn * 162 + z) * 162) + y) * 3;
      p[0] = 0; p[1] = 0; p[2] = 0;
    }
  }

  // ---- load tile + halo 8 (w,ly fastest -> coalesced global reads) ----
  for (int ti = tid; ti < 32 * 32 * 3; ti += 1024) {
    int w = ti % 3, r = ti / 3, ly = r % 32, lz = r / 32;
    int z = gz0 - 8 + lz, y = gy0 - 8 + ly;
    uint64_t v = 0;
    if ((unsigned)z < 162u && (unsigned)y < 162u)
      v = bin[((n * 162 + z) * 162 + y) * 3 + w];
    Bt[LADDR(lz, ly) + w] = v;
  }
  __syncthreads();

  // ---- ge2 (C26>=2, not-endpoint) on halo 7 (30x30), row-triple tasks ----
  for (int ti = tid; ti < 30 * 30; ti += 1024) {
    int iy = ti % 30, iz = ti / 30;
    int lz = 1 + iz, ly = 1 + iy;
    int base = LADDR(lz, ly);
    uint64_t c0 = Bt[base], c1 = Bt[base + 1], c2c = Bt[base + 2];
    if ((c0 | c1 | c2c) == 0ull) { Ge[base] = 0; Ge[base+1] = 0; Ge[base+2] = 0; continue; }
    uint64_t R[3][3][3];
    LOAD_R(Bt, lz, ly)
#pragma unroll
    for (int w = 0; w < 3; ++w) {
      uint64_t Vv[3][3], Lb[3][3], Rb[3][3];
      EXPAND_W(w)
      uint64_t s = 0, c = 0;
#define ACC(bb) { uint64_t _b = (bb); c |= s & _b; s |= _b; }
#pragma unroll
      for (int dz = -1; dz <= 1; ++dz)
#pragma unroll
        for (int dy = -1; dy <= 1; ++dy) {
          ACC(NB(dz,dy,-1)); ACC(NB(dz,dy,1));
          if (dz != 0 || dy != 0) ACC(NB(dz,dy,0));
        }
#undef ACC
      Ge[base + w] = c;
    }
  }
  __syncthreads();

  // ---- 8 subfield passes, halo 7-k, row-triple tasks ----
  const int PLZ[8] = {1,0,1,0,1,0,1,0};   // lz parity (xo=0 -> z even -> lz odd)
  const int PLY[8] = {1,1,0,0,1,1,0,0};   // ly parity
#pragma unroll
  for (int k = 0; k < 8; ++k) {
    const int h = 7 - k, cnt1 = 8 + h;
    const uint64_t xmask = (k < 4) ? 0x5555555555555555ull : 0xAAAAAAAAAAAAAAAAull;
    const int s0 = 8 - h;
    const int slz = s0 + ((s0 ^ PLZ[k]) & 1);
    const int sly = s0 + ((s0 ^ PLY[k]) & 1);
    for (int ti = tid; ti < cnt1 * cnt1; ti += 1024) {
      int iy = ti % cnt1, iz = ti / cnt1;
      int lz = slz + 2 * iz, ly = sly + 2 * iy;
      int base = LADDR(lz, ly);
      uint64_t ctr[3], act[3];
#pragma unroll
      for (int w = 0; w < 3; ++w) {
        ctr[w] = Bt[base + w];
        act[w] = ctr[w] & xmask & Ge[base + w];
      }
      if ((act[0] | act[1] | act[2]) == 0ull) continue;
      uint64_t R[3][3][3];
      LOAD_R(Bt, lz, ly)
#pragma unroll
      for (int w = 0; w < 3; ++w) {
        if (act[w] == 0ull) continue;
        uint64_t Vv[3][3], Lb[3][3], Rb[3][3];
        EXPAND_W(w)

        // C6 exact 3-bit counter over the 6 faces
        uint64_t on = 0, tw = 0, fo = 0;
#define C6ADD(b) { uint64_t _u = on & (b); on ^= (b); uint64_t _v = tw & _u; tw ^= _u; fo |= _v; }
        C6ADD(NB(-1,0,0)) C6ADD(NB(1,0,0)) C6ADD(NB(0,-1,0))
        C6ADD(NB(0,1,0))  C6ADD(NB(0,0,-1)) C6ADD(NB(0,0,1))
#undef C6ADD
        uint64_t c6eq5 = fo & on & ~tw;
        uint64_t c6le4 = ~(fo & (on | tw));

        // carry-save ==1 detectors over 18 then 26 neighbors
        uint64_t s = 0, c2 = 0;
#define CS(b) { uint64_t _b = (b); c2 |= s & _b; s |= _b; }
        CS(NB(-1,0,0)) CS(NB(1,0,0)) CS(NB(0,-1,0)) CS(NB(0,1,0)) CS(NB(0,0,-1)) CS(NB(0,0,1))
        CS(NB(-1,-1,0)) CS(NB(-1,1,0)) CS(NB(-1,0,-1)) CS(NB(-1,0,1))
        CS(NB(1,-1,0))  CS(NB(1,1,0))  CS(NB(1,0,-1))  CS(NB(1,0,1))
        CS(NB(0,-1,-1)) CS(NB(0,-1,1)) CS(NB(0,1,-1))  CS(NB(0,1,1))
        uint64_t e18 = s & ~c2;
        CS(NB(-1,-1,-1)) CS(NB(-1,-1,1)) CS(NB(-1,1,-1)) CS(NB(-1,1,1))
        CS(NB(1,-1,-1))  CS(NB(1,-1,1))  CS(NB(1,1,-1))  CS(NB(1,1,1))
        uint64_t e26 = s & ~c2;
#undef CS

        uint64_t del = (c6eq5 | e26) & act[w];
        // B/A patterns needed only where a candidate isn't already decided
        uint64_t need = act[w] & ~del & (e18 | c6le4);
        if (need != 0ull) {
          // B: corner set with its 6 octant face/edge cells all clear
          uint64_t badB = 0;
#pragma unroll
          for (int sz = -1; sz <= 1; sz += 2)
#pragma unroll
            for (int sy = -1; sy <= 1; sy += 2)
#pragma unroll
              for (int sx = -1; sx <= 1; sx += 2) {
                uint64_t oct = NB(sz,0,0) | NB(0,sy,0) | NB(0,0,sx)
                             | NB(sz,sy,0) | NB(sz,0,sx) | NB(0,sy,sx);
                badB |= NB(sz,sy,sx) & ~oct;
              }
          uint64_t b0ok = ~badB;

          // A: face clear with its full 4-cell in-plane ring set
          uint64_t badA = 0;
          badA |= ~NB(-1,0,0) & NB(-1,-1,0) & NB(-1,1,0) & NB(-1,0,-1) & NB(-1,0,1);
          badA |= ~NB( 1,0,0) & NB( 1,-1,0) & NB( 1,1,0) & NB( 1,0,-1) & NB( 1,0,1);
          badA |= ~NB(0,-1,0) & NB(-1,-1,0) & NB(1,-1,0) & NB(0,-1,-1) & NB(0,-1,1);
          badA |= ~NB(0, 1,0) & NB(-1, 1,0) & NB(1, 1,0) & NB(0, 1,-1) & NB(0, 1,1);
          badA |= ~NB(0,0,-1) & NB(-1,0,-1) & NB(1,0,-1) & NB(0,-1,-1) & NB(0,1,-1);
          badA |= ~NB(0,0, 1) & NB(-1,0, 1) & NB(1,0, 1) & NB(0,-1, 1) & NB(0,1, 1);
          uint64_t a0ok = ~badA;

          del |= ((e18 & b0ok) | (c6le4 & a0ok & b0ok)) & act[w];
        }
        if (del) Bt[base + w] = ctr[w] & ~del;
        // same-pass tasks never read each other's center rows (distance-2 rows
        // are outside the radius-1 neighborhood) -> fully race-free
      }
    }
    __syncthreads();
  }

  // ---- epilogue ----
  if (outf) {
    // final iteration: write float output for core directly from LDS
    for (int ti = tid; ti < 16 * 16 * 40; ti += 1024) {
      int g = ti % 40, r = ti / 40, iy = r % 16, iz = r / 16;
      int base = LADDR(8 + iz, 8 + iy);
      int bi = 1 + 4 * g;                 // padded x of first of 4 floats
      int wx = bi >> 6, sft = bi & 63;
      uint64_t v = Bt[base + wx] >> sft;
      if (sft > 60) v |= Bt[base + wx + 1] << (64 - sft);
      outf[((n * 160 + (gz0 + iz - 1)) * 160 + (gy0 + iy - 1)) * 40 + g] =
          make_float4((float)(v & 1u), (float)((v >> 1) & 1u),
                      (float)((v >> 2) & 1u), (float)((v >> 3) & 1u));
    }
  } else {
    // write core words back (disjoint across blocks)
    for (int ti = tid; ti < 16 * 16 * 3; ti += 1024) {
      int w = ti % 3, r = ti / 3, iy = r % 16, iz = r / 16;
      bout[((n * 162 + gz0 + iz) * 162 + (gy0 + iy)) * 3 + w] =
          Bt[LADDR(8 + iz, 8 + iy) + w];
    }
  }
}

// ---------------------------- launcher --------------------------------------
extern "C" void kernel_launch(void* const* d_in, const int* in_sizes, int n_in,
                              void* d_out, int out_size, void* d_ws, size_t ws_size,
                              hipStream_t stream) {
  const float* in = (const float*)d_in[0];
  float4* out = (float4*)d_out;
  uint64_t* A = (uint64_t*)d_ws;          // bitboard A
  uint64_t* B = A + NW;                   // bitboard B

  k_binarize<<<dim3((NWH * 64 + 255) / 256), dim3(256), 0, stream>>>(in, A);
  k_iter<<<dim3(200), dim3(1024), 0, stream>>>(A, B, nullptr, 1); // iter 1
  k_iter<<<dim3(200), dim3(1024), 0, stream>>>(B, A, nullptr, 0); // iter 2
  k_iter<<<dim3(200), dim3(1024), 0, stream>>>(A, B, nullptr, 0); // iter 3
  k_iter<<<dim3(200), dim3(1024), 0, stream>>>(B, A, nullptr, 0); // iter 4
  k_iter<<<dim3(200), dim3(1024), 0, stream>>>(A, nullptr, out, 0); // iter 5 -> out
}

// Round 13
// 236.060 us; speedup vs baseline: 1.0737x; 1.0737x over previous
//
#include <hip/hip_runtime.h>
#include <stdint.h>

// No implicit FMA contraction: the JAX eager reference has none across ops;
// where XLA fuses we write fmaf() explicitly.
#pragma clang fp contract(off)

#define PDIM 162
#define NW   (2*PDIM*PDIM*3)   // 157464 words, 1.26 MB per bitboard
#define NWH  (NW/2)            // 78732
#define OD   160

// LDS tile: 32 z-rows x 32 y-rows x 3 words, addr lz*97 + ly*3 + w.
// 97 u64 = 194 dwords == 2 mod 32 (measured conflict-neutral, R11).
#define PZ 97
#define LADDR(lz,ly) ((lz)*PZ + (ly)*3)

// ---------------- threefry2x32, JAX partitionable scheme --------------------
__device__ __forceinline__ uint32_t rotl32(uint32_t x, uint32_t r) {
  return (x << r) | (x >> (32u - r));
}

__device__ __forceinline__ uint32_t threefry_bits(uint32_t idx) {
  const uint32_t ks0 = 0u, ks1 = 42u, ks2 = 0x1BD11BDAu ^ 0u ^ 42u;
  uint32_t x0 = 0u + ks0;
  uint32_t x1 = idx + ks1;
#define TFR(r) { x0 += x1; x1 = rotl32(x1, (r)); x1 ^= x0; }
  TFR(13u) TFR(15u) TFR(26u) TFR(6u)
  x0 += ks1; x1 += ks2 + 1u;
  TFR(17u) TFR(29u) TFR(16u) TFR(24u)
  x0 += ks2; x1 += ks0 + 2u;
  TFR(13u) TFR(15u) TFR(26u) TFR(6u)
  x0 += ks0; x1 += ks1 + 3u;
  TFR(17u) TFR(29u) TFR(16u) TFR(24u)
  x0 += ks1; x1 += ks2 + 4u;
  TFR(13u) TFR(15u) TFR(26u) TFR(6u)
  x0 += ks2; x1 += ks0 + 5u;
#undef TFR
  return x0 ^ x1;
}

// ------------- XLA-CPU (Cephes) float32 log replication ---------------------
__device__ __forceinline__ float xla_logf(float xin) {
  uint32_t bits = __float_as_uint(xin);
  float e = (float)((int)(bits >> 23) - 126);
  float x = __uint_as_float((bits & 0x007fffffu) | 0x3f000000u);
  const float SQRTHF = 0.707106781186547524f;
  bool lt = (x < SQRTHF);
  float tmp = lt ? x : 0.0f;
  e = e - (lt ? 1.0f : 0.0f);
  x = x - 1.0f;
  x = x + tmp;
  float z = x * x;
  float y = 7.0376836292e-2f;
  y = fmaf(y, x, -1.1514610310e-1f);
  y = fmaf(y, x,  1.1676998740e-1f);
  y = fmaf(y, x, -1.2420140846e-1f);
  y = fmaf(y, x,  1.4249322787e-1f);
  y = fmaf(y, x, -1.6668057665e-1f);
  y = fmaf(y, x,  2.0000714765e-1f);
  y = fmaf(y, x, -2.4999993993e-1f);
  y = fmaf(y, x,  3.3333331174e-1f);
  y = y * x;
  y = y * z;
  y = fmaf(e, -2.12194440e-4f, y);
  y = fmaf(-0.5f, z, y);
  x = x + y;
  x = fmaf(e, 0.693359375f, x);
  return x;
}

__device__ __forceinline__ float xla_log1pf(float x) {
  float for_large = xla_logf(x + 1.0f);
  float for_small = fmaf(-0.5f, x, 1.0f) * x;
  return (fabsf(x) < 1e-4f) ? for_small : for_large;
}

// one voxel's decision (exact JAX/XLA bit replication)
__device__ __forceinline__ bool bin_pred(const float* __restrict__ in, uint32_t w,
                                         uint32_t lane) {
  uint32_t row = w / 3u, wx = w - row * 3u;
  uint32_t n  = row / (uint32_t)(PDIM * PDIM);
  uint32_t rr = row - n * (uint32_t)(PDIM * PDIM);
  uint32_t z  = rr / (uint32_t)PDIM;
  uint32_t y  = rr - z * (uint32_t)PDIM;
  uint32_t x  = wx * 64u + lane;
  // pad voxels are provably 0: |0.33*noise| <= 6.08 < 18.42 = |log alpha(0)|
  if ((z - 1u) >= 160u || (y - 1u) >= 160u || (x - 1u) >= 160u) return false;
  float v = in[((n * 160u + (z - 1u)) * 160u + (y - 1u)) * 160u + (x - 1u)];
  uint32_t i = row * 162u + x;            // flat padded index for RNG
  uint32_t b = threefry_bits(i);
  float f  = __uint_as_float((b >> 9) | 0x3f800000u) - 1.0f;
  float uu = fmaxf(1e-8f, f + 1e-8f);
  float la = xla_logf((v + 1e-8f) / ((1.0f - v) + 1e-8f));
  float noise = xla_logf(uu) - xla_log1pf(-uu);
  float zs = la + noise * 0.33f;
  return (zs > 1.1920928955078125e-7f);   // logistic>0.5 iff z>2^-23
}

// ---------------------------- binarize --------------------------------------
// ILP-2: each wave produces TWO words (w and w+NW/2).
__global__ __launch_bounds__(256) void k_binarize(const float* __restrict__ in,
                                                  uint64_t* __restrict__ bits) {
  uint32_t t = blockIdx.x * 256u + threadIdx.x;
  uint32_t w0 = t >> 6, lane = t & 63u;
  if (w0 >= (uint32_t)NWH) return;        // wave-uniform
  uint32_t w1 = w0 + (uint32_t)NWH;
  bool p0 = bin_pred(in, w0, lane);
  bool p1 = bin_pred(in, w1, lane);
  uint64_t m0 = __ballot(p0);
  uint64_t m1 = __ballot(p1);
  if (lane == 0) { bits[w0] = m0; bits[w1] = m1; }
}

// ------------- per-word neighborhood from LDS row triples -------------------
#define NB(dz,dy,dx) ((dx)==-1 ? Lb[(dz)+1][(dy)+1] : ((dx)==1 ? Rb[(dz)+1][(dy)+1] : Vv[(dz)+1][(dy)+1]))

#define GATHER_W(SRC, lz, ly, w) \
  _Pragma("unroll") \
  for (int dz = 0; dz < 3; ++dz) \
    _Pragma("unroll") \
    for (int dy = 0; dy < 3; ++dy) { \
      int rb = LADDR((lz) + dz - 1, (ly) + dy - 1); \
      uint64_t r0 = SRC[rb], r1 = SRC[rb + 1], r2 = SRC[rb + 2]; \
      uint64_t b = ((w) == 0) ? r0 : (((w) == 1) ? r1 : r2); \
      uint64_t a = ((w) == 0) ? 0ull : (((w) == 1) ? r0 : r1); \
      uint64_t d = ((w) == 0) ? r1 : (((w) == 1) ? r2 : 0ull); \
      Vv[dz][dy] = b; \
      Lb[dz][dy] = (b << 1) | (a >> 63); \
      Rb[dz][dy] = (b >> 1) | (d << 63); \
    }

// ---------------------------- iteration kernel ------------------------------
// One block: 16x16 (z,y) core x full 192-bit x, halo 8 -> 32x32 LDS tile.
// B0 keeps the pristine iteration-start state; ge2 (not-endpoint) is computed
// LAZILY inside each subfield task from B0 -> no dedicated ge2 phase, 8
// barriers instead of 9. Parity: a pass's voxels never neighbor same-pass
// voxels (same parity => some coord differs by >=2), so pass 0 can use the Bt
// gather for both ge2 and the simple-check.
__global__ __launch_bounds__(1024) void k_iter(const uint64_t* __restrict__ bin,
                                               uint64_t* __restrict__ bout,
                                               float4* __restrict__ outf,
                                               int zero_pads) {
  __shared__ uint64_t Bt[32 * PZ];
  __shared__ uint64_t B0[32 * PZ];
  const int tid = threadIdx.x;
  const int bid = blockIdx.x;
  const int n  = bid / 100;
  const int rm = bid - n * 100;
  const int tz = rm / 10, ty = rm - tz * 10;
  const int gz0 = 1 + 16 * tz, gy0 = 1 + 16 * ty;   // both odd

  // Zero bout's pad rows (z or y in {0,161}) once per replay (block 0, iter 1).
  if (zero_pads && bid == 0) {
    for (int j = tid; j < 1288; j += 1024) {
      int nn, z, y;
      if (j < 648) { nn = j / 324; int r = j - nn * 324;
                     z = (r >= 162) ? 161 : 0; y = (r >= 162) ? r - 162 : r; }
      else { int j2 = j - 648; nn = j2 / 320; int r = j2 - nn * 320;
             y = (r >= 160) ? 161 : 0; z = 1 + ((r >= 160) ? r - 160 : r); }
      uint64_t* p = bout + (((nn * 162 + z) * 162) + y) * 3;
      p[0] = 0; p[1] = 0; p[2] = 0;
    }
  }

  // ---- load tile + halo 8; keep pristine copy in B0 ----
  for (int ti = tid; ti < 32 * 32 * 3; ti += 1024) {
    int w = ti % 3, r = ti / 3, ly = r % 32, lz = r / 32;
    int z = gz0 - 8 + lz, y = gy0 - 8 + ly;
    uint64_t v = 0;
    if ((unsigned)z < 162u && (unsigned)y < 162u)
      v = bin[((n * 162 + z) * 162 + y) * 3 + w];
    Bt[LADDR(lz, ly) + w] = v;
    B0[LADDR(lz, ly) + w] = v;
  }
  __syncthreads();

  // ---- 8 subfield passes, halo 7-k, lazy ge2 from B0 ----
  const int PLZ[8] = {1,0,1,0,1,0,1,0};   // lz parity (xo=0 -> z even -> lz odd)
  const int PLY[8] = {1,1,0,0,1,1,0,0};   // ly parity
#pragma unroll
  for (int k = 0; k < 8; ++k) {
    const int h = 7 - k, cnt1 = 8 + h;
    const uint64_t xmask = (k < 4) ? 0x5555555555555555ull : 0xAAAAAAAAAAAAAAAAull;
    const int s0 = 8 - h;
    const int slz = s0 + ((s0 ^ PLZ[k]) & 1);
    const int sly = s0 + ((s0 ^ PLY[k]) & 1);
    for (int ti = tid; ti < cnt1 * cnt1 * 3; ti += 1024) {
      int w = ti % 3, r = ti / 3, iy = r % cnt1, iz = r / cnt1;
      int lz = slz + 2 * iz, ly = sly + 2 * iy;
      int base = LADDR(lz, ly) + w;
      uint64_t center = Bt[base];
      uint64_t pre = center & xmask;
      if (pre == 0ull) continue;

      uint64_t Vv[3][3], Lb[3][3], Rb[3][3];
      // ge2 from iteration-start state (pass 0: Bt's neighborhood == start)
      if (k == 0) { GATHER_W(Bt, lz, ly, w) }
      else        { GATHER_W(B0, lz, ly, w) }
      uint64_t s = 0, c2 = 0;
#define CS(b) { uint64_t _b = (b); c2 |= s & _b; s |= _b; }
#pragma unroll
      for (int dz = -1; dz <= 1; ++dz)
#pragma unroll
        for (int dy = -1; dy <= 1; ++dy) {
          CS(NB(dz,dy,-1)); CS(NB(dz,dy,1));
          if (dz != 0 || dy != 0) CS(NB(dz,dy,0));
        }
      uint64_t act = pre & c2;            // img & subfield & not-endpoint
      if (act == 0ull) continue;

      // current-state neighborhood (pass 0 reuses the same gather)
      if (k != 0) { GATHER_W(Bt, lz, ly, w) }

      // C6 exact 3-bit counter over the 6 faces
      uint64_t on = 0, tw = 0, fo = 0;
#define C6ADD(b) { uint64_t _u = on & (b); on ^= (b); uint64_t _v = tw & _u; tw ^= _u; fo |= _v; }
      C6ADD(NB(-1,0,0)) C6ADD(NB(1,0,0)) C6ADD(NB(0,-1,0))
      C6ADD(NB(0,1,0))  C6ADD(NB(0,0,-1)) C6ADD(NB(0,0,1))
#undef C6ADD
      uint64_t c6eq5 = fo & on & ~tw;
      uint64_t c6le4 = ~(fo & (on | tw));

      // carry-save ==1 detectors over 18 then 26 neighbors (current state)
      s = 0; c2 = 0;
      CS(NB(-1,0,0)) CS(NB(1,0,0)) CS(NB(0,-1,0)) CS(NB(0,1,0)) CS(NB(0,0,-1)) CS(NB(0,0,1))
      CS(NB(-1,-1,0)) CS(NB(-1,1,0)) CS(NB(-1,0,-1)) CS(NB(-1,0,1))
      CS(NB(1,-1,0))  CS(NB(1,1,0))  CS(NB(1,0,-1))  CS(NB(1,0,1))
      CS(NB(0,-1,-1)) CS(NB(0,-1,1)) CS(NB(0,1,-1))  CS(NB(0,1,1))
      uint64_t e18 = s & ~c2;
      CS(NB(-1,-1,-1)) CS(NB(-1,-1,1)) CS(NB(-1,1,-1)) CS(NB(-1,1,1))
      CS(NB(1,-1,-1))  CS(NB(1,-1,1))  CS(NB(1,1,-1))  CS(NB(1,1,1))
      uint64_t e26 = s & ~c2;
#undef CS

      uint64_t del = (c6eq5 | e26) & act;
      // B/A patterns only where a candidate isn't already decided
      uint64_t need = act & ~del & (e18 | c6le4);
      if (need != 0ull) {
        // B: corner set with its 6 octant face/edge cells all clear
        uint64_t badB = 0;
#pragma unroll
        for (int sz = -1; sz <= 1; sz += 2)
#pragma unroll
          for (int sy = -1; sy <= 1; sy += 2)
#pragma unroll
            for (int sx = -1; sx <= 1; sx += 2) {
              uint64_t oct = NB(sz,0,0) | NB(0,sy,0) | NB(0,0,sx)
                           | NB(sz,sy,0) | NB(sz,0,sx) | NB(0,sy,sx);
              badB |= NB(sz,sy,sx) & ~oct;
            }
        uint64_t b0ok = ~badB;

        // A: face clear with its full 4-cell in-plane ring set
        uint64_t badA = 0;
        badA |= ~NB(-1,0,0) & NB(-1,-1,0) & NB(-1,1,0) & NB(-1,0,-1) & NB(-1,0,1);
        badA |= ~NB( 1,0,0) & NB( 1,-1,0) & NB( 1,1,0) & NB( 1,0,-1) & NB( 1,0,1);
        badA |= ~NB(0,-1,0) & NB(-1,-1,0) & NB(1,-1,0) & NB(0,-1,-1) & NB(0,-1,1);
        badA |= ~NB(0, 1,0) & NB(-1, 1,0) & NB(1, 1,0) & NB(0, 1,-1) & NB(0, 1,1);
        badA |= ~NB(0,0,-1) & NB(-1,0,-1) & NB(1,0,-1) & NB(0,-1,-1) & NB(0,1,-1);
        badA |= ~NB(0,0, 1) & NB(-1,0, 1) & NB(1,0, 1) & NB(0,-1, 1) & NB(0,1, 1);
        uint64_t a0ok = ~badA;

        del |= ((e18 & b0ok) | (c6le4 & a0ok & b0ok)) & act;
      }
      if (del) Bt[base] = center & ~del;
      // readers only consume non-updated-parity bits; tearing-safe (R5 arg)
    }
    __syncthreads();
  }

  // ---- epilogue ----
  if (outf) {
    // final iteration: write float output for core directly from LDS
    for (int ti = tid; ti < 16 * 16 * 40; ti += 1024) {
      int g = ti % 40, r = ti / 40, iy = r % 16, iz = r / 16;
      int base = LADDR(8 + iz, 8 + iy);
      int bi = 1 + 4 * g;                 // padded x of first of 4 floats
      int wx = bi >> 6, sft = bi & 63;
      uint64_t v = Bt[base + wx] >> sft;
      if (sft > 60) v |= Bt[base + wx + 1] << (64 - sft);
      outf[((n * 160 + (gz0 + iz - 1)) * 160 + (gy0 + iy - 1)) * 40 + g] =
          make_float4((float)(v & 1u), (float)((v >> 1) & 1u),
                      (float)((v >> 2) & 1u), (float)((v >> 3) & 1u));
    }
  } else {
    // write core words back (disjoint across blocks)
    for (int ti = tid; ti < 16 * 16 * 3; ti += 1024) {
      int w = ti % 3, r = ti / 3, iy = r % 16, iz = r / 16;
      bout[((n * 162 + gz0 + iz) * 162 + (gy0 + iy)) * 3 + w] =
          Bt[LADDR(8 + iz, 8 + iy) + w];
    }
  }
}

// ---------------------------- launcher --------------------------------------
extern "C" void kernel_launch(void* const* d_in, const int* in_sizes, int n_in,
                              void* d_out, int out_size, void* d_ws, size_t ws_size,
                              hipStream_t stream) {
  const float* in = (const float*)d_in[0];
  float4* out = (float4*)d_out;
  uint64_t* A = (uint64_t*)d_ws;          // bitboard A
  uint64_t* B = A + NW;                   // bitboard B

  k_binarize<<<dim3((NWH * 64 + 255) / 256), dim3(256), 0, stream>>>(in, A);
  k_iter<<<dim3(200), dim3(1024), 0, stream>>>(A, B, nullptr, 1); // iter 1
  k_iter<<<dim3(200), dim3(1024), 0, stream>>>(B, A, nullptr, 0); // iter 2
  k_iter<<<dim3(200), dim3(1024), 0, stream>>>(A, B, nullptr, 0); // iter 3
  k_iter<<<dim3(200), dim3(1024), 0, stream>>>(B, A, nullptr, 0); // iter 4
  k_iter<<<dim3(200), dim3(1024), 0, stream>>>(A, nullptr, out, 0); // iter 5 -> out
}

// Round 14
// 222.043 us; speedup vs baseline: 1.1415x; 1.0631x over previous
//
#include <hip/hip_runtime.h>
#include <stdint.h>

// No implicit FMA contraction: the JAX eager reference has none across ops;
// where XLA fuses we write fmaf() explicitly.
#pragma clang fp contract(off)

#define PDIM 162
#define NW   (2*PDIM*PDIM*3)   // 157464 words, 1.26 MB per bitboard
#define NWH  (NW/2)            // 78732
#define OD   160

// LDS tile: 32 z-rows x 32 y-rows x 3 words, addr lz*97 + ly*3 + w.
// 97 u64 = 194 dwords == 2 mod 32 (measured conflict-neutral, R11).
#define PZ 97
#define LADDR(lz,ly) ((lz)*PZ + (ly)*3)

// ---------------- threefry2x32, JAX partitionable scheme --------------------
__device__ __forceinline__ uint32_t rotl32(uint32_t x, uint32_t r) {
  return (x << r) | (x >> (32u - r));
}

__device__ __forceinline__ uint32_t threefry_bits(uint32_t idx) {
  const uint32_t ks0 = 0u, ks1 = 42u, ks2 = 0x1BD11BDAu ^ 0u ^ 42u;
  uint32_t x0 = 0u + ks0;
  uint32_t x1 = idx + ks1;
#define TFR(r) { x0 += x1; x1 = rotl32(x1, (r)); x1 ^= x0; }
  TFR(13u) TFR(15u) TFR(26u) TFR(6u)
  x0 += ks1; x1 += ks2 + 1u;
  TFR(17u) TFR(29u) TFR(16u) TFR(24u)
  x0 += ks2; x1 += ks0 + 2u;
  TFR(13u) TFR(15u) TFR(26u) TFR(6u)
  x0 += ks0; x1 += ks1 + 3u;
  TFR(17u) TFR(29u) TFR(16u) TFR(24u)
  x0 += ks1; x1 += ks2 + 4u;
  TFR(13u) TFR(15u) TFR(26u) TFR(6u)
  x0 += ks2; x1 += ks0 + 5u;
#undef TFR
  return x0 ^ x1;
}

// ------------- XLA-CPU (Cephes) float32 log replication ---------------------
__device__ __forceinline__ float xla_logf(float xin) {
  uint32_t bits = __float_as_uint(xin);
  float e = (float)((int)(bits >> 23) - 126);
  float x = __uint_as_float((bits & 0x007fffffu) | 0x3f000000u);
  const float SQRTHF = 0.707106781186547524f;
  bool lt = (x < SQRTHF);
  float tmp = lt ? x : 0.0f;
  e = e - (lt ? 1.0f : 0.0f);
  x = x - 1.0f;
  x = x + tmp;
  float z = x * x;
  float y = 7.0376836292e-2f;
  y = fmaf(y, x, -1.1514610310e-1f);
  y = fmaf(y, x,  1.1676998740e-1f);
  y = fmaf(y, x, -1.2420140846e-1f);
  y = fmaf(y, x,  1.4249322787e-1f);
  y = fmaf(y, x, -1.6668057665e-1f);
  y = fmaf(y, x,  2.0000714765e-1f);
  y = fmaf(y, x, -2.4999993993e-1f);
  y = fmaf(y, x,  3.3333331174e-1f);
  y = y * x;
  y = y * z;
  y = fmaf(e, -2.12194440e-4f, y);
  y = fmaf(-0.5f, z, y);
  x = x + y;
  x = fmaf(e, 0.693359375f, x);
  return x;
}

__device__ __forceinline__ float xla_log1pf(float x) {
  float for_large = xla_logf(x + 1.0f);
  float for_small = fmaf(-0.5f, x, 1.0f) * x;
  return (fabsf(x) < 1e-4f) ? for_small : for_large;
}

// one voxel's decision (exact JAX/XLA bit replication)
__device__ __forceinline__ bool bin_pred(const float* __restrict__ in, uint32_t w,
                                         uint32_t lane) {
  uint32_t row = w / 3u, wx = w - row * 3u;
  uint32_t n  = row / (uint32_t)(PDIM * PDIM);
  uint32_t rr = row - n * (uint32_t)(PDIM * PDIM);
  uint32_t z  = rr / (uint32_t)PDIM;
  uint32_t y  = rr - z * (uint32_t)PDIM;
  uint32_t x  = wx * 64u + lane;
  // pad voxels are provably 0: |0.33*noise| <= 6.08 < 18.42 = |log alpha(0)|
  if ((z - 1u) >= 160u || (y - 1u) >= 160u || (x - 1u) >= 160u) return false;
  float v = in[((n * 160u + (z - 1u)) * 160u + (y - 1u)) * 160u + (x - 1u)];
  uint32_t i = row * 162u + x;            // flat padded index for RNG
  uint32_t b = threefry_bits(i);
  float f  = __uint_as_float((b >> 9) | 0x3f800000u) - 1.0f;
  float uu = fmaxf(1e-8f, f + 1e-8f);
  float la = xla_logf((v + 1e-8f) / ((1.0f - v) + 1e-8f));
  float noise = xla_logf(uu) - xla_log1pf(-uu);
  float zs = la + noise * 0.33f;
  return (zs > 1.1920928955078125e-7f);   // logistic>0.5 iff z>2^-23
}

// ---------------------------- binarize --------------------------------------
// ILP-2: each wave produces TWO words (w and w+NW/2).
__global__ __launch_bounds__(256) void k_binarize(const float* __restrict__ in,
                                                  uint64_t* __restrict__ bits) {
  uint32_t t = blockIdx.x * 256u + threadIdx.x;
  uint32_t w0 = t >> 6, lane = t & 63u;
  if (w0 >= (uint32_t)NWH) return;        // wave-uniform
  uint32_t w1 = w0 + (uint32_t)NWH;
  bool p0 = bin_pred(in, w0, lane);
  bool p1 = bin_pred(in, w1, lane);
  uint64_t m0 = __ballot(p0);
  uint64_t m1 = __ballot(p1);
  if (lane == 0) { bits[w0] = m0; bits[w1] = m1; }
}

// ------------- per-word neighborhood from LDS row triples -------------------
#define NB(dz,dy,dx) ((dx)==-1 ? Lb[(dz)+1][(dy)+1] : ((dx)==1 ? Rb[(dz)+1][(dy)+1] : Vv[(dz)+1][(dy)+1]))

#define GATHER_W(SRC, lz, ly, w) \
  _Pragma("unroll") \
  for (int dz = 0; dz < 3; ++dz) \
    _Pragma("unroll") \
    for (int dy = 0; dy < 3; ++dy) { \
      int rb = LADDR((lz) + dz - 1, (ly) + dy - 1); \
      uint64_t r0 = SRC[rb], r1 = SRC[rb + 1], r2 = SRC[rb + 2]; \
      uint64_t b = ((w) == 0) ? r0 : (((w) == 1) ? r1 : r2); \
      uint64_t a = ((w) == 0) ? 0ull : (((w) == 1) ? r0 : r1); \
      uint64_t d = ((w) == 0) ? r1 : (((w) == 1) ? r2 : 0ull); \
      Vv[dz][dy] = b; \
      Lb[dz][dy] = (b << 1) | (a >> 63); \
      Rb[dz][dy] = (b >> 1) | (d << 63); \
    }

// ---- balanced (OR, GE2) reduction: low serial depth for latency hiding ----
struct OG { uint64_t o, g; };
__device__ __forceinline__ OG og_leaf2(uint64_t a, uint64_t b) {
  OG r; r.o = a | b; r.g = a & b; return r;
}
__device__ __forceinline__ OG og_comb(OG a, OG b) {
  OG r; r.g = a.g | b.g | (a.o & b.o); r.o = a.o | b.o; return r;
}

// OG over the 18-neighborhood (faces+edges) and corners; both trees depth ~4.
#define OG_BUILD_18_C(og18, ogc) \
  OG a0 = og_leaf2(NB(-1,0,0), NB(1,0,0)); \
  OG a1 = og_leaf2(NB(0,-1,0), NB(0,1,0)); \
  OG a2 = og_leaf2(NB(0,0,-1), NB(0,0,1)); \
  OG e0 = og_leaf2(NB(-1,-1,0), NB(-1,1,0)); \
  OG e1 = og_leaf2(NB(-1,0,-1), NB(-1,0,1)); \
  OG e2 = og_leaf2(NB(1,-1,0),  NB(1,1,0)); \
  OG e3 = og_leaf2(NB(1,0,-1),  NB(1,0,1)); \
  OG e4 = og_leaf2(NB(0,-1,-1), NB(0,-1,1)); \
  OG e5 = og_leaf2(NB(0,1,-1),  NB(0,1,1)); \
  OG t0 = og_comb(a0, a1); \
  OG t1 = og_comb(a2, e0); \
  OG t2 = og_comb(e1, e2); \
  OG t3 = og_comb(e3, e4); \
  OG og18 = og_comb(og_comb(og_comb(t0, t1), og_comb(t2, t3)), e5); \
  OG c0 = og_leaf2(NB(-1,-1,-1), NB(-1,-1,1)); \
  OG c1 = og_leaf2(NB(-1,1,-1),  NB(-1,1,1)); \
  OG c2 = og_leaf2(NB(1,-1,-1),  NB(1,-1,1)); \
  OG c3 = og_leaf2(NB(1,1,-1),   NB(1,1,1)); \
  OG ogc = og_comb(og_comb(c0, c1), og_comb(c2, c3));

// ---------------------------- iteration kernel ------------------------------
// One block: 16x16 (z,y) core x full 192-bit x, halo 8 -> 32x32 LDS tile.
// ge2 on halo 7, then 8 subfield passes with shrinking halo; writes core only
// (or, final iteration, the float output directly from LDS).
__global__ __launch_bounds__(1024) void k_iter(const uint64_t* __restrict__ bin,
                                               uint64_t* __restrict__ bout,
                                               float4* __restrict__ outf,
                                               int zero_pads) {
  __shared__ uint64_t Bt[32 * PZ];
  __shared__ uint64_t Ge[32 * PZ];
  const int tid = threadIdx.x;
  const int bid = blockIdx.x;
  const int n  = bid / 100;
  const int rm = bid - n * 100;
  const int tz = rm / 10, ty = rm - tz * 10;
  const int gz0 = 1 + 16 * tz, gy0 = 1 + 16 * ty;   // both odd

  // Zero bout's pad rows (z or y in {0,161}) once per replay (block 0, iter 1).
  if (zero_pads && bid == 0) {
    for (int j = tid; j < 1288; j += 1024) {
      int nn, z, y;
      if (j < 648) { nn = j / 324; int r = j - nn * 324;
                     z = (r >= 162) ? 161 : 0; y = (r >= 162) ? r - 162 : r; }
      else { int j2 = j - 648; nn = j2 / 320; int r = j2 - nn * 320;
             y = (r >= 160) ? 161 : 0; z = 1 + ((r >= 160) ? r - 160 : r); }
      uint64_t* p = bout + (((nn * 162 + z) * 162) + y) * 3;
      p[0] = 0; p[1] = 0; p[2] = 0;
    }
  }

  // ---- load tile + halo 8 (w,ly fastest -> coalesced global reads) ----
  for (int ti = tid; ti < 32 * 32 * 3; ti += 1024) {
    int w = ti % 3, r = ti / 3, ly = r % 32, lz = r / 32;
    int z = gz0 - 8 + lz, y = gy0 - 8 + ly;
    uint64_t v = 0;
    if ((unsigned)z < 162u && (unsigned)y < 162u)
      v = bin[((n * 162 + z) * 162 + y) * 3 + w];
    Bt[LADDR(lz, ly) + w] = v;
  }
  __syncthreads();

  // ---- ge2 (C26>=2, not-endpoint) on halo 7 (30x30), tree reduction ----
  for (int ti = tid; ti < 30 * 30 * 3; ti += 1024) {
    int w = ti % 3, r = ti / 3, iy = r % 30, iz = r / 30;
    int lz = 1 + iz, ly = 1 + iy;
    int base = LADDR(lz, ly) + w;
    uint64_t res = 0;
    if (Bt[base] != 0ull) {               // ge2 only consumed ANDed with center
      uint64_t Vv[3][3], Lb[3][3], Rb[3][3];
      GATHER_W(Bt, lz, ly, w)
      OG_BUILD_18_C(og18, ogc)
      res = og_comb(og18, ogc).g;         // GE2 over all 26
    }
    Ge[base] = res;
  }
  __syncthreads();

  // ---- 8 subfield passes, halo 7-k, parity per reference offsets order ----
  const int PLZ[8] = {1,0,1,0,1,0,1,0};   // lz parity (xo=0 -> z even -> lz odd)
  const int PLY[8] = {1,1,0,0,1,1,0,0};   // ly parity
#pragma unroll
  for (int k = 0; k < 8; ++k) {
    const int h = 7 - k, cnt1 = 8 + h;
    const uint64_t xmask = (k < 4) ? 0x5555555555555555ull : 0xAAAAAAAAAAAAAAAAull;
    const int s0 = 8 - h;
    const int slz = s0 + ((s0 ^ PLZ[k]) & 1);
    const int sly = s0 + ((s0 ^ PLY[k]) & 1);
    for (int ti = tid; ti < cnt1 * cnt1 * 3; ti += 1024) {
      int w = ti % 3, r = ti / 3, iy = r % cnt1, iz = r / cnt1;
      int lz = slz + 2 * iz, ly = sly + 2 * iy;
      int base = LADDR(lz, ly) + w;
      uint64_t center = Bt[base];
      uint64_t act = center & xmask & Ge[base];
      if (act == 0ull) continue;
      uint64_t Vv[3][3], Lb[3][3], Rb[3][3];
      GATHER_W(Bt, lz, ly, w)

      // tree (OR,GE2) over 18-set and corners
      OG_BUILD_18_C(og18, ogc)
      OG og26 = og_comb(og18, ogc);
      uint64_t e18 = og18.o & ~og18.g;    // C18 == 1
      uint64_t e26 = og26.o & ~og26.g;    // C26 == 1

      // C6 via complemented faces: eq5 = exactly-1 missing, le4 = >=2 missing
      uint64_t m0f = ~NB(-1,0,0), m1f = ~NB(1,0,0), m2f = ~NB(0,-1,0);
      uint64_t m3f = ~NB(0,1,0),  m4f = ~NB(0,0,-1), m5f = ~NB(0,0,1);
      OG p0 = og_leaf2(m0f, m1f);
      OG p1 = og_leaf2(m2f, m3f);
      OG p2 = og_leaf2(m4f, m5f);
      OG pm = og_comb(og_comb(p0, p1), p2);
      uint64_t c6eq5 = pm.o & ~pm.g;
      uint64_t c6le4 = pm.g;

      uint64_t del = (c6eq5 | e26) & act;
      // B/A patterns only where a candidate isn't already decided
      uint64_t need = act & ~del & (e18 | c6le4);
      if (need != 0ull) {
        // B: corner set with its 6 octant face/edge cells all clear
        uint64_t badB = 0;
#pragma unroll
        for (int sz = -1; sz <= 1; sz += 2)
#pragma unroll
          for (int sy = -1; sy <= 1; sy += 2)
#pragma unroll
            for (int sx = -1; sx <= 1; sx += 2) {
              uint64_t oct = NB(sz,0,0) | NB(0,sy,0) | NB(0,0,sx)
                           | NB(sz,sy,0) | NB(sz,0,sx) | NB(0,sy,sx);
              badB |= NB(sz,sy,sx) & ~oct;
            }
        uint64_t b0ok = ~badB;

        // A: face clear with its full 4-cell in-plane ring set
        uint64_t badA = 0;
        badA |= ~NB(-1,0,0) & NB(-1,-1,0) & NB(-1,1,0) & NB(-1,0,-1) & NB(-1,0,1);
        badA |= ~NB( 1,0,0) & NB( 1,-1,0) & NB( 1,1,0) & NB( 1,0,-1) & NB( 1,0,1);
        badA |= ~NB(0,-1,0) & NB(-1,-1,0) & NB(1,-1,0) & NB(0,-1,-1) & NB(0,-1,1);
        badA |= ~NB(0, 1,0) & NB(-1, 1,0) & NB(1, 1,0) & NB(0, 1,-1) & NB(0, 1,1);
        badA |= ~NB(0,0,-1) & NB(-1,0,-1) & NB(1,0,-1) & NB(0,-1,-1) & NB(0,1,-1);
        badA |= ~NB(0,0, 1) & NB(-1,0, 1) & NB(1,0, 1) & NB(0,-1, 1) & NB(0,1, 1);
        uint64_t a0ok = ~badA;

        del |= ((e18 & b0ok) | (c6le4 & a0ok & b0ok)) & act;
      }
      if (del) Bt[base] = center & ~del;
      // readers only consume non-updated-parity bits; tearing-safe (R5 arg)
    }
    __syncthreads();
  }

  // ---- epilogue ----
  if (outf) {
    // final iteration: write float output for core directly from LDS
    for (int ti = tid; ti < 16 * 16 * 40; ti += 1024) {
      int g = ti % 40, r = ti / 40, iy = r % 16, iz = r / 16;
      int base = LADDR(8 + iz, 8 + iy);
      int bi = 1 + 4 * g;                 // padded x of first of 4 floats
      int wx = bi >> 6, sft = bi & 63;
      uint64_t v = Bt[base + wx] >> sft;
      if (sft > 60) v |= Bt[base + wx + 1] << (64 - sft);
      outf[((n * 160 + (gz0 + iz - 1)) * 160 + (gy0 + iy - 1)) * 40 + g] =
          make_float4((float)(v & 1u), (float)((v >> 1) & 1u),
                      (float)((v >> 2) & 1u), (float)((v >> 3) & 1u));
    }
  } else {
    // write core words back (disjoint across blocks)
    for (int ti = tid; ti < 16 * 16 * 3; ti += 1024) {
      int w = ti % 3, r = ti / 3, iy = r % 16, iz = r / 16;
      bout[((n * 162 + gz0 + iz) * 162 + (gy0 + iy)) * 3 + w] =
          Bt[LADDR(8 + iz, 8 + iy) + w];
    }
  }
}

// ---------------------------- launcher --------------------------------------
extern "C" void kernel_launch(void* const* d_in, const int* in_sizes, int n_in,
                              void* d_out, int out_size, void* d_ws, size_t ws_size,
                              hipStream_t stream) {
  const float* in = (const float*)d_in[0];
  float4* out = (float4*)d_out;
  uint64_t* A = (uint64_t*)d_ws;          // bitboard A
  uint64_t* B = A + NW;                   // bitboard B

  k_binarize<<<dim3((NWH * 64 + 255) / 256), dim3(256), 0, stream>>>(in, A);
  k_iter<<<dim3(200), dim3(1024), 0, stream>>>(A, B, nullptr, 1); // iter 1
  k_iter<<<dim3(200), dim3(1024), 0, stream>>>(B, A, nullptr, 0); // iter 2
  k_iter<<<dim3(200), dim3(1024), 0, stream>>>(A, B, nullptr, 0); // iter 3
  k_iter<<<dim3(200), dim3(1024), 0, stream>>>(B, A, nullptr, 0); // iter 4
  k_iter<<<dim3(200), dim3(1024), 0, stream>>>(A, nullptr, out, 0); // iter 5 -> out
}